// Round 1
// baseline (352.359 us; speedup 1.0000x reference)
//
#include <hip/hip_runtime.h>

#define OUT_H 7
#define OUT_W 7
#define NSAMP (OUT_H * OUT_W * 2 * 2)   // 196 sample points per ROI
#define CCH 256
#define FH 256
#define FW 256
#define HW (FH * FW)
#define CHW (CCH * HW)
#define SCALE 0.25f

__global__ __launch_bounds__(256) void rroi_align_kernel(
    const float* __restrict__ feat,
    const float* __restrict__ rois,
    float* __restrict__ out)
{
    const int n  = blockIdx.x;   // ROI index
    const int gy = blockIdx.y;   // which 1/7th of this ROI's outputs
    const int t  = threadIdx.x;

    __shared__ int    s_off[NSAMP];
    __shared__ float4 s_w[NSAMP];
    __shared__ int    s_b;

    const float* r = rois + (size_t)n * 6;

    if (t < NSAMP) {
        float cx = r[1] * SCALE, cy = r[2] * SCALE;
        float rw = fmaxf(r[3] * SCALE, 0.f), rh = fmaxf(r[4] * SCALE, 0.f);
        float theta = r[5];
        float bin_h = rh * (1.f / OUT_H), bin_w = rw * (1.f / OUT_W);

        int sx = t & 1, sy = (t >> 1) & 1, pp = t >> 2;
        int pw = pp % OUT_W, ph = pp / OUT_W;

        float yy = bin_h * ((float)ph + ((float)sy + 0.5f) * 0.5f) - rh * 0.5f;
        float xx = bin_w * ((float)pw + ((float)sx + 0.5f) * 0.5f) - rw * 0.5f;
        float ct = cosf(theta), st = sinf(theta);
        float x = xx * ct + yy * st + cx;
        float y = yy * ct - xx * st + cy;

        float v = (y > -1.f && y < (float)FH && x > -1.f && x < (float)FW) ? 1.f : 0.f;
        float ycl = fminf(fmaxf(y, 0.f), (float)(FH - 1));
        float xcl = fminf(fmaxf(x, 0.f), (float)(FW - 1));
        float y0f = fminf(fmaxf(floorf(ycl), 0.f), (float)(FH - 2));
        float x0f = fminf(fmaxf(floorf(xcl), 0.f), (float)(FW - 2));
        int y0 = (int)y0f, x0 = (int)x0f;
        float ly = ycl - y0f, lx = xcl - x0f;
        float hy = 1.f - ly, hx = 1.f - lx;

        s_off[t] = y0 * FW + x0;
        s_w[t]   = make_float4(hy * hx * v, hy * lx * v, ly * hx * v, ly * lx * v);
        if (t == 0) s_b = (int)r[0];
    }
    __syncthreads();

    const float* fb = feat + (size_t)s_b * CHW;

    // 49 output "rows" of 256 (flat index c*49 + ph*7 + pw, linear in memory),
    // split 7 ways across gridDim.y; each block does 7 iterations.
    #pragma unroll
    for (int i = 0; i < 7; ++i) {
        int flat = (gy * 7 + i) * 256 + t;     // 0 .. 12543
        int c  = flat / 49;
        int pp = flat - c * 49;
        const float* fc = fb + (size_t)c * HW;

        float acc = 0.f;
        #pragma unroll
        for (int k = 0; k < 4; ++k) {
            int sid = pp * 4 + k;
            int off = s_off[sid];
            float4 w = s_w[sid];
            acc += w.x * fc[off]      + w.y * fc[off + 1]
                 + w.z * fc[off + FW] + w.w * fc[off + FW + 1];
        }
        out[(size_t)n * (CCH * OUT_H * OUT_W) + flat] = acc * 0.25f;
    }
}

extern "C" void kernel_launch(void* const* d_in, const int* in_sizes, int n_in,
                              void* d_out, int out_size, void* d_ws, size_t ws_size,
                              hipStream_t stream)
{
    const float* feat = (const float*)d_in[0];
    const float* rois = (const float*)d_in[1];
    float* out = (float*)d_out;
    int N = in_sizes[1] / 6;

    dim3 grid(N, 7);
    rroi_align_kernel<<<grid, 256, 0, stream>>>(feat, rois, out);
}

// Round 2
// 273.137 us; speedup vs baseline: 1.2900x; 1.2900x over previous
//
#include <hip/hip_runtime.h>

#define OUT_H 7
#define OUT_W 7
#define NSAMP (OUT_H * OUT_W * 2 * 2)   // 196 sample points per ROI
#define CCH 256
#define FH 256
#define FW 256
#define HW (FH * FW)
#define CHW (CCH * HW)
#define SCALE 0.25f

// Single-block bitonic sort: order ROIs by (batch, cy-bucket, cx-bucket) so
// spatially-overlapping ROIs are adjacent in the permutation.
__global__ __launch_bounds__(1024) void sort_rois_kernel(
    const float* __restrict__ rois, int N, int* __restrict__ perm)
{
    __shared__ int s_key[1024];
    __shared__ int s_val[1024];
    const int t = threadIdx.x;

    int key = 0x7FFFFFFF, val = 0;
    if (t < N) {
        const float* r = rois + (size_t)t * 6;
        int bi = (int)r[0];
        float cyf = r[2] * SCALE;   // 0..256 feature coords
        float cxf = r[1] * SCALE;
        int cyb = min(15, max(0, (int)(cyf * (1.f / 16.f))));
        int cxb = min(15, max(0, (int)(cxf * (1.f / 16.f))));
        key = (bi << 18) | (cyb << 14) | (cxb << 10) | t;  // unique keys
        val = t;
    }
    s_key[t] = key; s_val[t] = val;
    __syncthreads();

    for (int k = 2; k <= 1024; k <<= 1) {
        for (int j = k >> 1; j > 0; j >>= 1) {
            int ixj = t ^ j;
            if (ixj > t) {
                int a = s_key[t], bkey = s_key[ixj];
                bool up = ((t & k) == 0);
                if ((a > bkey) == up) {
                    s_key[t] = bkey; s_key[ixj] = a;
                    int av = s_val[t]; s_val[t] = s_val[ixj]; s_val[ixj] = av;
                }
            }
            __syncthreads();
        }
    }
    if (t < N) perm[t] = s_val[t];
}

// Block mapping: xcd = b&7 (dispatch round-robins XCDs), each XCD owns P
// consecutive sorted ROIs and sweeps the 7 channel-chunks (gy) over time.
// Co-resident blocks on one XCD therefore share a small, hot feature region.
__global__ __launch_bounds__(256) void rroi_align_kernel(
    const float* __restrict__ feat,
    const float* __restrict__ rois,
    const int* __restrict__ perm,
    int N, int P,
    float* __restrict__ out)
{
    const int b   = blockIdx.x;
    const int xcd = b & 7;
    const int s   = b >> 3;
    const int gy  = s / P;          // channel-chunk, varies slowest per XCD
    const int rl  = s - gy * P;
    const int r   = xcd * P + rl;   // sorted ROI position
    if (r >= N) return;
    const int n = perm[r];          // original ROI index
    const int t = threadIdx.x;

    __shared__ int   s_off[NSAMP];
    __shared__ float s_w0[NSAMP], s_w1[NSAMP], s_w2[NSAMP], s_w3[NSAMP];
    __shared__ int   s_b;

    const float* rr = rois + (size_t)n * 6;

    if (t < NSAMP) {
        float cx = rr[1] * SCALE, cy = rr[2] * SCALE;
        float rw = fmaxf(rr[3] * SCALE, 0.f), rh = fmaxf(rr[4] * SCALE, 0.f);
        float theta = rr[5];
        float bin_h = rh * (1.f / OUT_H), bin_w = rw * (1.f / OUT_W);

        int sx = t & 1, sy = (t >> 1) & 1, pp = t >> 2;
        int pw = pp % OUT_W, ph = pp / OUT_W;

        float yy = bin_h * ((float)ph + ((float)sy + 0.5f) * 0.5f) - rh * 0.5f;
        float xx = bin_w * ((float)pw + ((float)sx + 0.5f) * 0.5f) - rw * 0.5f;
        float ct = cosf(theta), st = sinf(theta);
        float x = xx * ct + yy * st + cx;
        float y = yy * ct - xx * st + cy;

        float v = (y > -1.f && y < (float)FH && x > -1.f && x < (float)FW) ? 0.25f : 0.f;
        float ycl = fminf(fmaxf(y, 0.f), (float)(FH - 1));
        float xcl = fminf(fmaxf(x, 0.f), (float)(FW - 1));
        float y0f = fminf(fmaxf(floorf(ycl), 0.f), (float)(FH - 2));
        float x0f = fminf(fmaxf(floorf(xcl), 0.f), (float)(FW - 2));
        int y0 = (int)y0f, x0 = (int)x0f;
        float ly = ycl - y0f, lx = xcl - x0f;
        float hy = 1.f - ly, hx = 1.f - lx;

        s_off[t] = y0 * FW + x0;
        // premultiplied by 1/(S*S) = 0.25 (folded into v)
        s_w0[t] = hy * hx * v;
        s_w1[t] = hy * lx * v;
        s_w2[t] = ly * hx * v;
        s_w3[t] = ly * lx * v;
        if (t == 0) s_b = (int)rr[0];
    }
    __syncthreads();

    const float* fb = feat + (size_t)s_b * CHW;

    #pragma unroll
    for (int i = 0; i < 7; ++i) {
        int flat = (gy * 7 + i) * 256 + t;     // 0 .. 12543
        int c  = flat / 49;
        int pp = flat - c * 49;
        const float* fc = fb + (size_t)c * HW;

        float acc = 0.f;
        #pragma unroll
        for (int k = 0; k < 4; ++k) {
            int sid = pp * 4 + k;
            const float* p = fc + s_off[sid];
            acc += s_w0[sid] * p[0]  + s_w1[sid] * p[1]
                 + s_w2[sid] * p[FW] + s_w3[sid] * p[FW + 1];
        }
        out[(size_t)n * (CCH * OUT_H * OUT_W) + flat] = acc;
    }
}

extern "C" void kernel_launch(void* const* d_in, const int* in_sizes, int n_in,
                              void* d_out, int out_size, void* d_ws, size_t ws_size,
                              hipStream_t stream)
{
    const float* feat = (const float*)d_in[0];
    const float* rois = (const float*)d_in[1];
    float* out = (float*)d_out;
    int N = in_sizes[1] / 6;
    int* perm = (int*)d_ws;

    sort_rois_kernel<<<1, 1024, 0, stream>>>(rois, N, perm);

    int P  = (N + 7) / 8;           // ROIs per XCD
    int NB = 8 * P * 7;
    rroi_align_kernel<<<NB, 256, 0, stream>>>(feat, rois, perm, N, P, out);
}

// Round 3
// 201.381 us; speedup vs baseline: 1.7497x; 1.3563x over previous
//
#include <hip/hip_runtime.h>

#define OUT_H 7
#define OUT_W 7
#define NSAMP (OUT_H * OUT_W * 2 * 2)   // 196 sample points per ROI
#define CCH 256
#define FH 256
#define FW 256
#define HW (FH * FW)
#define CHW (CCH * HW)
#define SCALE 0.25f

// ---------- bf16 helpers (bit-exact, RNE) ----------
__device__ __forceinline__ unsigned short f2bf(float f) {
    unsigned int u = __float_as_uint(f);
    u += 0x7FFFu + ((u >> 16) & 1u);      // round-to-nearest-even (finite inputs)
    return (unsigned short)(u >> 16);
}
#define BFLO(u) __uint_as_float((u) << 16)
#define BFHI(u) __uint_as_float((u) & 0xFFFF0000u)

// ==================================================================
// Main path: transpose BCHW fp32 -> BHWC bf16 (L3-resident), then
// perfectly-coalesced channel-vector gather.
// ==================================================================

// Transpose: per batch, (C=256, S=65536) -> (S, C) with bf16 pack.
// Tile: 64 channels x 32 spatial. Reads coalesced in s, writes coalesced in c.
__global__ __launch_bounds__(256) void transpose_kernel(
    const float* __restrict__ feat, unsigned int* __restrict__ featT)
{
    __shared__ float tile[64][33];
    const int t  = threadIdx.x;
    const int tx = t & 31;
    const int ty = t >> 5;                 // 0..7
    const int s0 = blockIdx.x * 32;
    const int c0 = blockIdx.y * 64;
    const int b  = blockIdx.z;

    const float* inb = feat + (size_t)b * CHW;
    #pragma unroll
    for (int j = 0; j < 8; ++j) {
        int c = j * 8 + ty;
        tile[c][tx] = inb[(size_t)(c0 + c) * HW + (s0 + tx)];
    }
    __syncthreads();

    // out pixel layout: 256 bf16 = 128 uints per pixel
    unsigned int* outb = featT + (size_t)b * (HW * 128);
    #pragma unroll
    for (int j = 0; j < 4; ++j) {
        int r = j * 8 + ty;                // spatial row within tile, 0..31
        unsigned int lo = f2bf(tile[2 * tx][r]);
        unsigned int hi = f2bf(tile[2 * tx + 1][r]);
        outb[(size_t)(s0 + r) * 128 + (c0 >> 1) + tx] = lo | (hi << 16);
    }
}

// Gather: block = (ROI, half of the 49 bins). Lane cl owns channels 4cl..4cl+3;
// each corner read is a contiguous 512B vector -> one dense dwordx2 per wave.
__global__ __launch_bounds__(256) void gather_kernel(
    const unsigned short* __restrict__ featT,
    const float* __restrict__ rois,
    float* __restrict__ out)
{
    const int n  = blockIdx.x;
    const int gy = blockIdx.y;             // 0: bins 0..24, 1: bins 25..48
    const int t  = threadIdx.x;

    __shared__ int   s_off[NSAMP];         // pixel index with batch baked in
    __shared__ float s_w0[NSAMP], s_w1[NSAMP], s_w2[NSAMP], s_w3[NSAMP];

    const float* rr = rois + (size_t)n * 6;

    if (t < NSAMP) {
        float cx = rr[1] * SCALE, cy = rr[2] * SCALE;
        float rw = fmaxf(rr[3] * SCALE, 0.f), rh = fmaxf(rr[4] * SCALE, 0.f);
        float theta = rr[5];
        float bin_h = rh * (1.f / OUT_H), bin_w = rw * (1.f / OUT_W);

        int sx = t & 1, sy = (t >> 1) & 1, pp = t >> 2;
        int pw = pp % OUT_W, ph = pp / OUT_W;

        float yy = bin_h * ((float)ph + ((float)sy + 0.5f) * 0.5f) - rh * 0.5f;
        float xx = bin_w * ((float)pw + ((float)sx + 0.5f) * 0.5f) - rw * 0.5f;
        float ct = cosf(theta), st = sinf(theta);
        float x = xx * ct + yy * st + cx;
        float y = yy * ct - xx * st + cy;

        float v = (y > -1.f && y < (float)FH && x > -1.f && x < (float)FW) ? 0.25f : 0.f;
        float ycl = fminf(fmaxf(y, 0.f), (float)(FH - 1));
        float xcl = fminf(fmaxf(x, 0.f), (float)(FW - 1));
        float y0f = fminf(fmaxf(floorf(ycl), 0.f), (float)(FH - 2));
        float x0f = fminf(fmaxf(floorf(xcl), 0.f), (float)(FW - 2));
        int y0 = (int)y0f, x0 = (int)x0f;
        float ly = ycl - y0f, lx = xcl - x0f;
        float hy = 1.f - ly, hx = 1.f - lx;

        s_off[t] = ((int)rr[0]) * HW + y0 * FW + x0;   // batch baked in
        s_w0[t] = hy * hx * v;
        s_w1[t] = hy * lx * v;
        s_w2[t] = ly * hx * v;
        s_w3[t] = ly * lx * v;
    }
    __syncthreads();

    const int cl = t & 63;                 // channel quad: channels 4cl..4cl+3
    const int w  = t >> 6;                 // wave id 0..3
    const int start = gy * 25;
    const int cnt   = 25 - gy;             // 25 or 24 bins

    for (int i = w; i < cnt; i += 4) {
        int pp = start + i;
        float a0 = 0.f, a1 = 0.f, a2 = 0.f, a3 = 0.f;
        #pragma unroll
        for (int k = 0; k < 4; ++k) {
            int sid = pp * 4 + k;
            size_t base = (size_t)s_off[sid] * 256 + 4 * cl;   // bf16 elem units
            float w0 = s_w0[sid], w1 = s_w1[sid], w2 = s_w2[sid], w3 = s_w3[sid];
            uint2 v00 = *(const uint2*)(featT + base);                 // (y0,x0)
            uint2 v01 = *(const uint2*)(featT + base + 256);           // (y0,x1)
            uint2 v10 = *(const uint2*)(featT + base + 256 * FW);      // (y1,x0)
            uint2 v11 = *(const uint2*)(featT + base + 256 * (FW + 1));// (y1,x1)
            a0 += w0 * BFLO(v00.x) + w1 * BFLO(v01.x) + w2 * BFLO(v10.x) + w3 * BFLO(v11.x);
            a1 += w0 * BFHI(v00.x) + w1 * BFHI(v01.x) + w2 * BFHI(v10.x) + w3 * BFHI(v11.x);
            a2 += w0 * BFLO(v00.y) + w1 * BFLO(v01.y) + w2 * BFLO(v10.y) + w3 * BFLO(v11.y);
            a3 += w0 * BFHI(v00.y) + w1 * BFHI(v01.y) + w2 * BFHI(v10.y) + w3 * BFHI(v11.y);
        }
        float* o = out + (size_t)n * (CCH * OUT_H * OUT_W) + (size_t)(4 * cl) * 49 + pp;
        o[0]   = a0;
        o[49]  = a1;
        o[98]  = a2;
        o[147] = a3;
    }
}

// ==================================================================
// Fallback path (ws too small): round-2 sorted clustered gather.
// ==================================================================
__global__ __launch_bounds__(1024) void sort_rois_kernel(
    const float* __restrict__ rois, int N, int* __restrict__ perm)
{
    __shared__ int s_key[1024];
    __shared__ int s_val[1024];
    const int t = threadIdx.x;

    int key = 0x7FFFFFFF, val = 0;
    if (t < N) {
        const float* r = rois + (size_t)t * 6;
        int bi = (int)r[0];
        int cyb = min(15, max(0, (int)(r[2] * SCALE * (1.f / 16.f))));
        int cxb = min(15, max(0, (int)(r[1] * SCALE * (1.f / 16.f))));
        key = (bi << 18) | (cyb << 14) | (cxb << 10) | t;
        val = t;
    }
    s_key[t] = key; s_val[t] = val;
    __syncthreads();

    for (int k = 2; k <= 1024; k <<= 1) {
        for (int j = k >> 1; j > 0; j >>= 1) {
            int ixj = t ^ j;
            if (ixj > t) {
                int a = s_key[t], bkey = s_key[ixj];
                bool up = ((t & k) == 0);
                if ((a > bkey) == up) {
                    s_key[t] = bkey; s_key[ixj] = a;
                    int av = s_val[t]; s_val[t] = s_val[ixj]; s_val[ixj] = av;
                }
            }
            __syncthreads();
        }
    }
    if (t < N) perm[t] = s_val[t];
}

__global__ __launch_bounds__(256) void rroi_align_fallback(
    const float* __restrict__ feat,
    const float* __restrict__ rois,
    const int* __restrict__ perm,
    int N, int P,
    float* __restrict__ out)
{
    const int b   = blockIdx.x;
    const int xcd = b & 7;
    const int s   = b >> 3;
    const int gy  = s / P;
    const int rl  = s - gy * P;
    const int r   = xcd * P + rl;
    if (r >= N) return;
    const int n = perm ? perm[r] : r;
    const int t = threadIdx.x;

    __shared__ int   s_off[NSAMP];
    __shared__ float s_w0[NSAMP], s_w1[NSAMP], s_w2[NSAMP], s_w3[NSAMP];
    __shared__ int   s_b;

    const float* rr = rois + (size_t)n * 6;

    if (t < NSAMP) {
        float cx = rr[1] * SCALE, cy = rr[2] * SCALE;
        float rw = fmaxf(rr[3] * SCALE, 0.f), rh = fmaxf(rr[4] * SCALE, 0.f);
        float theta = rr[5];
        float bin_h = rh * (1.f / OUT_H), bin_w = rw * (1.f / OUT_W);

        int sx = t & 1, sy = (t >> 1) & 1, pp = t >> 2;
        int pw = pp % OUT_W, ph = pp / OUT_W;

        float yy = bin_h * ((float)ph + ((float)sy + 0.5f) * 0.5f) - rh * 0.5f;
        float xx = bin_w * ((float)pw + ((float)sx + 0.5f) * 0.5f) - rw * 0.5f;
        float ct = cosf(theta), st = sinf(theta);
        float x = xx * ct + yy * st + cx;
        float y = yy * ct - xx * st + cy;

        float v = (y > -1.f && y < (float)FH && x > -1.f && x < (float)FW) ? 0.25f : 0.f;
        float ycl = fminf(fmaxf(y, 0.f), (float)(FH - 1));
        float xcl = fminf(fmaxf(x, 0.f), (float)(FW - 1));
        float y0f = fminf(fmaxf(floorf(ycl), 0.f), (float)(FH - 2));
        float x0f = fminf(fmaxf(floorf(xcl), 0.f), (float)(FW - 2));
        int y0 = (int)y0f, x0 = (int)x0f;
        float ly = ycl - y0f, lx = xcl - x0f;
        float hy = 1.f - ly, hx = 1.f - lx;

        s_off[t] = y0 * FW + x0;
        s_w0[t] = hy * hx * v;
        s_w1[t] = hy * lx * v;
        s_w2[t] = ly * hx * v;
        s_w3[t] = ly * lx * v;
        if (t == 0) s_b = (int)rr[0];
    }
    __syncthreads();

    const float* fb = feat + (size_t)s_b * CHW;

    #pragma unroll
    for (int i = 0; i < 7; ++i) {
        int flat = (gy * 7 + i) * 256 + t;
        int c  = flat / 49;
        int pp = flat - c * 49;
        const float* fc = fb + (size_t)c * HW;

        float acc = 0.f;
        #pragma unroll
        for (int k = 0; k < 4; ++k) {
            int sid = pp * 4 + k;
            const float* p = fc + s_off[sid];
            acc += s_w0[sid] * p[0]  + s_w1[sid] * p[1]
                 + s_w2[sid] * p[FW] + s_w3[sid] * p[FW + 1];
        }
        out[(size_t)n * (CCH * OUT_H * OUT_W) + flat] = acc;
    }
}

extern "C" void kernel_launch(void* const* d_in, const int* in_sizes, int n_in,
                              void* d_out, int out_size, void* d_ws, size_t ws_size,
                              hipStream_t stream)
{
    const float* feat = (const float*)d_in[0];
    const float* rois = (const float*)d_in[1];
    float* out = (float*)d_out;
    int N = in_sizes[1] / 6;

    const size_t needT = (size_t)4 * HW * CCH * 2;   // 128 MB bf16 transposed copy

    if (ws_size >= needT) {
        unsigned int* featT = (unsigned int*)d_ws;
        dim3 tg(HW / 32, CCH / 64, 4);
        transpose_kernel<<<tg, 256, 0, stream>>>(feat, featT);
        dim3 gg(N, 2);
        gather_kernel<<<gg, 256, 0, stream>>>((const unsigned short*)d_ws, rois, out);
    } else if (ws_size >= 4096 && N <= 1024) {
        int* perm = (int*)d_ws;
        sort_rois_kernel<<<1, 1024, 0, stream>>>(rois, N, perm);
        int P  = (N + 7) / 8;
        int NB = 8 * P * 7;
        rroi_align_fallback<<<NB, 256, 0, stream>>>(feat, rois, perm, N, P, out);
    } else {
        int P  = (N + 7) / 8;
        int NB = 8 * P * 7;
        rroi_align_fallback<<<NB, 256, 0, stream>>>(feat, rois, (const int*)nullptr, N, P, out);
    }
}